// Round 1
// baseline (4495.304 us; speedup 1.0000x reference)
//
#include <hip/hip_runtime.h>
#include <hip/hip_bf16.h>

// ---------------- problem constants ----------------
constexpr int HDIM = 23;       // hidden size
constexpr int G3   = 69;       // 3*H gate rows
constexpr int RPAD = 80;       // gate rows padded (16 chunks * 5 rows)
constexpr int TT   = 512;      // timesteps
constexpr int BB   = 2048;     // batch
constexpr int FIN  = 32;       // layer-0 input features
constexpr int FHID = 46;       // 2*H (layers 1..2 input features)
constexpr int KPH  = 48;       // padded feature dim for bf16 buffers
constexpr int NOUT = 8;
constexpr int BT   = 16;       // batch elems per block
constexpr int RPC  = 5;        // rows per chunk

__device__ __forceinline__ float sigm(float x) {
    // 1/(1+2^(-x*log2e))
    float e = exp2f(x * -1.4426950408889634f);
    return 1.0f / (1.0f + e);
}
__device__ __forceinline__ float tanh_(float x) {
    // tanh = 1 - 2/(e^{2x}+1)
    float e = exp2f(x * 2.8853900817779268f);
    return 1.0f - 2.0f / (e + 1.0f);
}
__device__ __forceinline__ float bf2f(unsigned int u16) {
    return __uint_as_float(u16 << 16);
}

// One direction of one GRU layer.  grid = (BB/BT, 2 dirs), block = 256.
// Lanes: bsub = tid&15 (batch), chunk = tid>>4 (5 gate rows each, rows padded to 80).
// L0: input = raw x [B][T][FIN] fp32, normalized on the fly.
// !L0: input = bf16 buffer [T][B][KPH] (cols 46..47 are garbage but hit zero weights).
template <bool L0>
__global__ __launch_bounds__(256) void gru_layer(
    const void* __restrict__ in_, const float* __restrict__ fmean,
    const float* __restrict__ fstd, const float* __restrict__ wih_g,
    const float* __restrict__ whh_g, const float* __restrict__ bih_g,
    const float* __restrict__ bhh_g, __hip_bfloat16* __restrict__ outbuf,
    float* __restrict__ lastbuf, int lastOnly)
{
    constexpr int KIN = L0 ? FIN : FHID;
    constexpr int KP  = L0 ? 32  : KPH;

    const int dir   = blockIdx.y;
    const int tid   = threadIdx.x;
    const int bsub  = tid & 15;
    const int chunk = tid >> 4;
    const int bg    = blockIdx.x * BT + bsub;

    __shared__ float whh_s[RPAD * 24];
    __shared__ float wih_s[RPAD * KP];
    __shared__ float bih_s[RPAD], bhh_s[RPAD];
    __shared__ float gsum[2 * HDIM * BT];          // rows 0..45 (r,z): xg+hg
    __shared__ float gnx[HDIM * BT];               // n rows: input part (+b_ih)
    __shared__ float gnh[HDIM * BT];               // n rows: hidden part (+b_hh)
    __shared__ float hbuf[24 * BT];                // h state, k-major [24][BT]

    const float* wih_d = wih_g + dir * G3 * KIN;
    const float* whh_d = whh_g + dir * G3 * HDIM;

    for (int idx = tid; idx < RPAD * 24; idx += 256) {
        int j = idx / 24, k = idx % 24;
        whh_s[idx] = (j < G3 && k < HDIM) ? whh_d[j * HDIM + k] : 0.f;
    }
    for (int idx = tid; idx < RPAD * KP; idx += 256) {
        int j = idx / KP, k = idx % KP;
        wih_s[idx] = (j < G3 && k < KIN) ? wih_d[j * KIN + k] : 0.f;
    }
    for (int idx = tid; idx < RPAD; idx += 256) {
        bih_s[idx] = (idx < G3) ? bih_g[dir * G3 + idx] : 0.f;
        bhh_s[idx] = (idx < G3) ? bhh_g[dir * G3 + idx] : 0.f;
    }
    for (int idx = tid; idx < 24 * BT; idx += 256) hbuf[idx] = 0.f;

    // layer-0 normalization: x' = x*a + c, with exact-compare semantics
    float an[L0 ? FIN : 1], cn[L0 ? FIN : 1];
    if constexpr (L0) {
        #pragma unroll
        for (int f = 0; f < FIN; f++) {
            float sd = fstd[f];
            float sa = (sd == 0.f) ? 1.f : sd;
            float a  = (sa == 1.f) ? 0.f : 1.f / sa;
            an[f] = a;
            cn[f] = -fmean[f] * a;
        }
    }
    __syncthreads();

    const int j0    = chunk * RPC;
    const int steps = (lastOnly && dir == 1) ? 1 : TT;

    for (int s = 0; s < steps; s++) {
        const int t = dir ? (TT - 1 - s) : s;

        // ---- load h into registers (broadcast across chunk groups) ----
        float hreg[24];
        #pragma unroll
        for (int k = 0; k < 24; k++) hreg[k] = hbuf[k * BT + bsub];

        float acch[RPC], accx[RPC];
        #pragma unroll
        for (int r = 0; r < RPC; r++) {
            acch[r] = bhh_s[j0 + r];
            accx[r] = bih_s[j0 + r];
        }

        // ---- hidden matvec: 5 rows x 24 ----
        #pragma unroll
        for (int r = 0; r < RPC; r++) {
            const float4* wr = (const float4*)&whh_s[(j0 + r) * 24];
            #pragma unroll
            for (int k4 = 0; k4 < 6; k4++) {
                float4 w = wr[k4];
                acch[r] += w.x * hreg[k4 * 4 + 0] + w.y * hreg[k4 * 4 + 1] +
                           w.z * hreg[k4 * 4 + 2] + w.w * hreg[k4 * 4 + 3];
            }
        }

        // ---- input matvec ----
        if constexpr (L0) {
            const float* xrow = (const float*)in_ + ((size_t)bg * TT + t) * FIN;
            #pragma unroll
            for (int c = 0; c < FIN / 4; c++) {
                float4 xv = ((const float4*)xrow)[c];
                float x0 = xv.x * an[c * 4 + 0] + cn[c * 4 + 0];
                float x1 = xv.y * an[c * 4 + 1] + cn[c * 4 + 1];
                float x2 = xv.z * an[c * 4 + 2] + cn[c * 4 + 2];
                float x3 = xv.w * an[c * 4 + 3] + cn[c * 4 + 3];
                #pragma unroll
                for (int r = 0; r < RPC; r++) {
                    float4 w = ((const float4*)&wih_s[(j0 + r) * KP])[c];
                    accx[r] += w.x * x0 + w.y * x1 + w.z * x2 + w.w * x3;
                }
            }
        } else {
            const unsigned short* xrow =
                (const unsigned short*)in_ + ((size_t)t * BB + bg) * KP;
            #pragma unroll
            for (int c = 0; c < KP / 8; c++) {
                uint4 u = ((const uint4*)xrow)[c];
                float xv[8];
                xv[0] = bf2f(u.x & 0xffffu); xv[1] = bf2f(u.x >> 16);
                xv[2] = bf2f(u.y & 0xffffu); xv[3] = bf2f(u.y >> 16);
                xv[4] = bf2f(u.z & 0xffffu); xv[5] = bf2f(u.z >> 16);
                xv[6] = bf2f(u.w & 0xffffu); xv[7] = bf2f(u.w >> 16);
                #pragma unroll
                for (int r = 0; r < RPC; r++) {
                    const float4* wr = (const float4*)&wih_s[(j0 + r) * KP + c * 8];
                    float4 w0 = wr[0], w1 = wr[1];
                    accx[r] += w0.x * xv[0] + w0.y * xv[1] + w0.z * xv[2] +
                               w0.w * xv[3] + w1.x * xv[4] + w1.y * xv[5] +
                               w1.z * xv[6] + w1.w * xv[7];
                }
            }
        }

        // ---- publish gate pre-activations ----
        #pragma unroll
        for (int r = 0; r < RPC; r++) {
            int j = j0 + r;
            if (j < 2 * HDIM) {
                gsum[j * BT + bsub] = acch[r] + accx[r];
            } else if (j < G3) {
                gnx[(j - 2 * HDIM) * BT + bsub] = accx[r];
                gnh[(j - 2 * HDIM) * BT + bsub] = acch[r];
            }
        }
        __syncthreads();

        // ---- combine: 23*16 = 368 items over 256 threads ----
        for (int item = tid; item < HDIM * BT; item += 256) {
            int b = item & 15, i = item >> 4;
            float rg   = sigm(gsum[i * BT + b]);
            float zg   = sigm(gsum[(HDIM + i) * BT + b]);
            float ng   = tanh_(gnx[i * BT + b] + rg * gnh[i * BT + b]);
            float hold = hbuf[i * BT + b];
            float hnew = ng + zg * (hold - ng);
            hbuf[i * BT + b] = hnew;
            int bglob = blockIdx.x * BT + b;
            if (!lastOnly) {
                outbuf[((size_t)t * BB + bglob) * KPH + dir * HDIM + i] =
                    __float2bfloat16(hnew);
            } else if (t == TT - 1) {
                lastbuf[bglob * KPH + dir * HDIM + i] = hnew;
            }
        }
        __syncthreads();
    }
}

__global__ __launch_bounds__(256) void fc_kernel(
    const float* __restrict__ last, const float* __restrict__ fcw,
    const float* __restrict__ fcb, const float* __restrict__ ostd,
    const float* __restrict__ omean, float* __restrict__ out)
{
    int idx = blockIdx.x * 256 + threadIdx.x;
    if (idx >= BB * NOUT) return;
    int b = idx >> 3, o = idx & 7;
    float acc = fcb[o];
    const float* lr = last + b * KPH;
    const float* wr = fcw + o * FHID;
    #pragma unroll
    for (int i = 0; i < FHID; i++) acc += lr[i] * wr[i];
    out[idx] = acc * ostd[o] + omean[o];
}

extern "C" void kernel_launch(void* const* d_in, const int* in_sizes, int n_in,
                              void* d_out, int out_size, void* d_ws,
                              size_t ws_size, hipStream_t stream)
{
    const float* x     = (const float*)d_in[0];
    const float* fmean = (const float*)d_in[1];
    const float* fstd  = (const float*)d_in[2];
    const float* omean = (const float*)d_in[3];
    const float* ostd  = (const float*)d_in[4];
    const float* wih0  = (const float*)d_in[5];
    const float* whh0  = (const float*)d_in[6];
    const float* bih0  = (const float*)d_in[7];
    const float* bhh0  = (const float*)d_in[8];
    const float* wihr  = (const float*)d_in[9];
    const float* whhr  = (const float*)d_in[10];
    const float* bihr  = (const float*)d_in[11];
    const float* bhhr  = (const float*)d_in[12];
    const float* fcw   = (const float*)d_in[13];
    const float* fcb   = (const float*)d_in[14];

    char* ws = (char*)d_ws;
    const size_t bufBytes = (size_t)TT * BB * KPH * sizeof(__hip_bfloat16); // 96 MiB
    __hip_bfloat16* buf0 = (__hip_bfloat16*)ws;
    __hip_bfloat16* buf1 = (__hip_bfloat16*)(ws + bufBytes);
    float* lastb         = (float*)(ws + 2 * bufBytes);

    dim3 grid(BB / BT, 2);

    // layer 0: raw x -> buf0
    gru_layer<true><<<grid, 256, 0, stream>>>(x, fmean, fstd, wih0, whh0, bih0,
                                              bhh0, buf0, nullptr, 0);
    // layer 1: buf0 -> buf1
    gru_layer<false><<<grid, 256, 0, stream>>>(
        buf0, nullptr, nullptr, wihr + 0 * 2 * G3 * FHID, whhr + 0 * 2 * G3 * HDIM,
        bihr + 0 * 2 * G3, bhhr + 0 * 2 * G3, buf1, nullptr, 0);
    // layer 2: buf1 -> last only (fwd full scan, bwd single step)
    gru_layer<false><<<grid, 256, 0, stream>>>(
        buf1, nullptr, nullptr, wihr + 1 * 2 * G3 * FHID, whhr + 1 * 2 * G3 * HDIM,
        bihr + 1 * 2 * G3, bhhr + 1 * 2 * G3, nullptr, lastb, 1);
    // fc + output denorm
    fc_kernel<<<(BB * NOUT + 255) / 256, 256, 0, stream>>>(lastb, fcw, fcb, ostd,
                                                           omean, (float*)d_out);
}

// Round 2
// 2462.644 us; speedup vs baseline: 1.8254x; 1.8254x over previous
//
#include <hip/hip_runtime.h>
#include <hip/hip_bf16.h>

constexpr int TT = 512, BB = 2048, KPH = 48, NOUT = 8;

__device__ __forceinline__ float sigm(float x) {
    return 1.f / (1.f + exp2f(x * -1.4426950408889634f));
}
__device__ __forceinline__ float tanh_(float x) {
    return 1.f - 2.f / (exp2f(x * 2.8853900817779268f) + 1.f);
}
__device__ __forceinline__ float bf2f(unsigned u) { return __uint_as_float(u << 16); }

// One direction of one GRU layer, time-batched.
// grid = (BB/8, 2 dirs), block = 192 = 24 row-chunks x 8 batch.
// Per 8-step group: stage inputs -> LDS (fp32), compute xg for 8 steps (high
// ILP, no h dependence), then 8 lean scan steps (hidden matvec from
// register-resident W_hh + gate combine). 2 blocks/CU hide barrier stalls.
template <bool L0>
__global__ __launch_bounds__(192) void gru_fused(
    const void* __restrict__ in_, const float* __restrict__ fmean,
    const float* __restrict__ fstd, const float* __restrict__ wih_g,
    const float* __restrict__ whh_g, const float* __restrict__ bih_g,
    const float* __restrict__ bhh_g, __hip_bfloat16* __restrict__ outbuf,
    float* __restrict__ lastbuf, int lastOnly)
{
    constexpr int KIN  = L0 ? 32 : 46;
    constexpr int XPAD = L0 ? 36 : 52;   // bank-conflict-free, 16B-aligned rows
    constexpr int KV4  = L0 ? 8 : 12;    // float4 cols actually read

    __shared__ __align__(16) float wih_s[72 * XPAD];
    __shared__ __align__(16) float whh_s[72 * 28];
    __shared__ __align__(16) float xin_s[64 * XPAD];  // [8 t][8 b][XPAD]
    __shared__ float xg_s[64 * 72];                   // [8 t][8 b][72 rows]
    __shared__ float ghid[72 * 8];                    // [row][b] hidden-side sums
    __shared__ __align__(16) float h_s[8 * 28];       // [b][28] h state
    __shared__ float bih_s[72], bhh_s[72];
    __shared__ __align__(16) float an_s[32], cn_s[32];

    const int tid = threadIdx.x;
    const int dir = blockIdx.y;
    const int c   = tid >> 3;      // row chunk 0..23 (rows 3c..3c+2, pad to 72)
    const int b   = tid & 7;       // batch sub-lane
    const int j0  = 3 * c;
    const int bg0 = blockIdx.x * 8;

    const float* wih_d = wih_g + dir * 69 * KIN;
    const float* whh_d = whh_g + dir * 69 * 23;

    for (int idx = tid; idx < 72 * XPAD; idx += 192) {
        int j = idx / XPAD, k = idx - j * XPAD;
        wih_s[idx] = (j < 69 && k < KIN) ? wih_d[j * KIN + k] : 0.f;
    }
    for (int idx = tid; idx < 72 * 28; idx += 192) {
        int j = idx / 28, k = idx - j * 28;
        whh_s[idx] = (j < 69 && k < 23) ? whh_d[j * 23 + k] : 0.f;
    }
    for (int idx = tid; idx < 72; idx += 192) {
        bih_s[idx] = (idx < 69) ? bih_g[dir * 69 + idx] : 0.f;
        bhh_s[idx] = (idx < 69) ? bhh_g[dir * 69 + idx] : 0.f;
    }
    for (int idx = tid; idx < 8 * 28; idx += 192) h_s[idx] = 0.f;
    if (L0 && tid < 32) {
        float sd = fstd[tid];
        float sa = (sd == 0.f) ? 1.f : sd;       // std==0 -> 1
        float a  = (sa == 1.f) ? 0.f : 1.f / sa; // adjusted std==1 -> zero feature
        an_s[tid] = a;
        cn_s[tid] = -fmean[tid] * a;
    }
    __syncthreads();

    // hidden-side weights live in registers for the whole kernel
    float4 wreg[3][7];
    float  bh[3], bi[3];
    #pragma unroll
    for (int r = 0; r < 3; ++r) {
        #pragma unroll
        for (int k4 = 0; k4 < 7; ++k4)
            wreg[r][k4] = *(const float4*)&whh_s[(j0 + r) * 28 + 4 * k4];
        bh[r] = bhh_s[j0 + r];
        bi[r] = bih_s[j0 + r];
    }

    const int ngroups = (lastOnly && dir == 1) ? 1 : 64;
    const int nsteps  = (lastOnly && dir == 1) ? 1 : 8;

    for (int g = 0; g < ngroups; ++g) {
        // ---- stage 8 timesteps of input into LDS (fp32) ----
        if constexpr (L0) {
            for (int p = 0; p < 3; ++p) {
                int tau = tid + 192 * p;
                if (tau < 512) {   // 8t x 8b x 8 float4
                    int tl = tau >> 6, bb_ = (tau >> 3) & 7, q = tau & 7;
                    int tg = dir ? (TT - 1 - (g * 8 + tl)) : (g * 8 + tl);
                    float4 xv = *(const float4*)((const float*)in_ +
                                 (((size_t)(bg0 + bb_) * TT + tg) * 32 + 4 * q));
                    float4 a4 = *(const float4*)&an_s[4 * q];
                    float4 c4 = *(const float4*)&cn_s[4 * q];
                    float4 o;
                    o.x = xv.x * a4.x + c4.x; o.y = xv.y * a4.y + c4.y;
                    o.z = xv.z * a4.z + c4.z; o.w = xv.w * a4.w + c4.w;
                    *(float4*)&xin_s[(tl * 8 + bb_) * XPAD + 4 * q] = o;
                }
            }
        } else {
            #pragma unroll
            for (int p = 0; p < 4; ++p) {   // 8t x 8b x 12 uint2 = 768 tasks
                int tau = tid + 192 * p;
                int tl = tau / 96, rem = tau - tl * 96;
                int bb_ = rem / 12, u = rem - bb_ * 12;
                int tg = dir ? (TT - 1 - (g * 8 + tl)) : (g * 8 + tl);
                uint2 v = *(const uint2*)((const unsigned short*)in_ +
                           (((size_t)tg * BB + bg0 + bb_) * KPH + 4 * u));
                float4 o;
                o.x = bf2f(v.x & 0xffffu); o.y = bf2f(v.x >> 16);
                o.z = bf2f(v.y & 0xffffu); o.w = bf2f(v.y >> 16);
                *(float4*)&xin_s[(tl * 8 + bb_) * XPAD + 4 * u] = o;
            }
        }
        __syncthreads();

        // ---- phase A: input-side gates for all 8 steps (no h dependence) ----
        float acc[8][3];
        #pragma unroll
        for (int t = 0; t < 8; ++t) {
            acc[t][0] = bi[0]; acc[t][1] = bi[1]; acc[t][2] = bi[2];
        }
        for (int k4 = 0; k4 < KV4; ++k4) {
            float4 w0 = *(const float4*)&wih_s[(j0 + 0) * XPAD + 4 * k4];
            float4 w1 = *(const float4*)&wih_s[(j0 + 1) * XPAD + 4 * k4];
            float4 w2 = *(const float4*)&wih_s[(j0 + 2) * XPAD + 4 * k4];
            #pragma unroll
            for (int t = 0; t < 8; ++t) {
                float4 xv = *(const float4*)&xin_s[(t * 8 + b) * XPAD + 4 * k4];
                acc[t][0] += w0.x * xv.x + w0.y * xv.y + w0.z * xv.z + w0.w * xv.w;
                acc[t][1] += w1.x * xv.x + w1.y * xv.y + w1.z * xv.z + w1.w * xv.w;
                acc[t][2] += w2.x * xv.x + w2.y * xv.y + w2.z * xv.z + w2.w * xv.w;
            }
        }
        #pragma unroll
        for (int t = 0; t < 8; ++t) {
            float* dst = &xg_s[(t * 8 + b) * 72 + j0];
            dst[0] = acc[t][0]; dst[1] = acc[t][1]; dst[2] = acc[t][2];
        }
        __syncthreads();

        // ---- 8 scan steps: hidden matvec + combine ----
        for (int s8 = 0; s8 < nsteps; ++s8) {
            float4 h4[7];
            #pragma unroll
            for (int k4 = 0; k4 < 7; ++k4)
                h4[k4] = *(const float4*)&h_s[b * 28 + 4 * k4];
            float a0 = bh[0], a1 = bh[1], a2 = bh[2];
            #pragma unroll
            for (int k4 = 0; k4 < 7; ++k4) {
                float4 x = h4[k4];
                float4 w;
                w = wreg[0][k4]; a0 += w.x * x.x + w.y * x.y + w.z * x.z + w.w * x.w;
                w = wreg[1][k4]; a1 += w.x * x.x + w.y * x.y + w.z * x.z + w.w * x.w;
                w = wreg[2][k4]; a2 += w.x * x.x + w.y * x.y + w.z * x.z + w.w * x.w;
            }
            ghid[(j0 + 0) * 8 + b] = a0;
            ghid[(j0 + 1) * 8 + b] = a1;
            ghid[(j0 + 2) * 8 + b] = a2;
            __syncthreads();

            if (tid < 184) {   // 23 hidden units x 8 batch
                int i = tid >> 3, bb_ = tid & 7;
                const float* xb = &xg_s[(s8 * 8 + bb_) * 72];
                float r_ = sigm(xb[i]      + ghid[i * 8 + bb_]);
                float z_ = sigm(xb[23 + i] + ghid[(23 + i) * 8 + bb_]);
                float n_ = tanh_(xb[46 + i] + r_ * ghid[(46 + i) * 8 + bb_]);
                float hold = h_s[bb_ * 28 + i];
                float hnew = n_ + z_ * (hold - n_);   // (1-z)n + z h
                h_s[bb_ * 28 + i] = hnew;
                int tg = dir ? (TT - 1 - (g * 8 + s8)) : (g * 8 + s8);
                if (!lastOnly) {
                    outbuf[((size_t)tg * BB + bg0 + bb_) * KPH + dir * 23 + i] =
                        __float2bfloat16(hnew);
                } else if (tg == TT - 1) {
                    lastbuf[(bg0 + bb_) * KPH + dir * 23 + i] = hnew;
                }
            }
            __syncthreads();
        }
    }
}

__global__ __launch_bounds__(256) void fc_kernel(
    const float* __restrict__ last, const float* __restrict__ fcw,
    const float* __restrict__ fcb, const float* __restrict__ ostd,
    const float* __restrict__ omean, float* __restrict__ out)
{
    int idx = blockIdx.x * 256 + threadIdx.x;
    if (idx >= BB * NOUT) return;
    int b = idx >> 3, o = idx & 7;
    float acc = fcb[o];
    const float* lr = last + b * KPH;
    const float* wr = fcw + o * 46;
    #pragma unroll
    for (int i = 0; i < 46; i++) acc += lr[i] * wr[i];
    out[idx] = acc * ostd[o] + omean[o];
}

extern "C" void kernel_launch(void* const* d_in, const int* in_sizes, int n_in,
                              void* d_out, int out_size, void* d_ws,
                              size_t ws_size, hipStream_t stream)
{
    const float* x     = (const float*)d_in[0];
    const float* fmean = (const float*)d_in[1];
    const float* fstd  = (const float*)d_in[2];
    const float* omean = (const float*)d_in[3];
    const float* ostd  = (const float*)d_in[4];
    const float* wih0  = (const float*)d_in[5];
    const float* whh0  = (const float*)d_in[6];
    const float* bih0  = (const float*)d_in[7];
    const float* bhh0  = (const float*)d_in[8];
    const float* wihr  = (const float*)d_in[9];
    const float* whhr  = (const float*)d_in[10];
    const float* bihr  = (const float*)d_in[11];
    const float* bhhr  = (const float*)d_in[12];
    const float* fcw   = (const float*)d_in[13];
    const float* fcb   = (const float*)d_in[14];

    char* ws = (char*)d_ws;
    const size_t bufBytes = (size_t)TT * BB * KPH * sizeof(__hip_bfloat16); // 96 MiB
    __hip_bfloat16* buf0 = (__hip_bfloat16*)ws;
    __hip_bfloat16* buf1 = (__hip_bfloat16*)(ws + bufBytes);
    float* lastb         = (float*)(ws + 2 * bufBytes);

    dim3 grid(BB / 8, 2);

    gru_fused<true><<<grid, 192, 0, stream>>>(x, fmean, fstd, wih0, whh0, bih0,
                                              bhh0, buf0, nullptr, 0);
    gru_fused<false><<<grid, 192, 0, stream>>>(
        buf0, nullptr, nullptr, wihr + 0 * 2 * 69 * 46, whhr + 0 * 2 * 69 * 23,
        bihr + 0 * 2 * 69, bhhr + 0 * 2 * 69, buf1, nullptr, 0);
    gru_fused<false><<<grid, 192, 0, stream>>>(
        buf1, nullptr, nullptr, wihr + 1 * 2 * 69 * 46, whhr + 1 * 2 * 69 * 23,
        bihr + 1 * 2 * 69, bhhr + 1 * 2 * 69, nullptr, lastb, 1);
    fc_kernel<<<(BB * NOUT + 255) / 256, 256, 0, stream>>>(lastb, fcw, fcb, ostd,
                                                           omean, (float*)d_out);
}